// Round 1
// 237.346 us; speedup vs baseline: 1.1214x; 1.1214x over previous
//
#include <hip/hip_runtime.h>
#include <stdint.h>

// Problem constants
#define BB    64
#define CC    100
#define NBPER 150
#define FEAT  2052
#define KP    2112      // FEAT padded to 33*64 for BK=64 MFMA loop
#define NOUT  2048
#define MR    6400      // BB*CC rows of x / support

typedef __attribute__((ext_vector_type(8))) short   short8;
typedef __attribute__((ext_vector_type(4))) float   floatx4;

__device__ __forceinline__ unsigned short f2bf(float f) {
  unsigned int u = __float_as_uint(f);
  u += 0x7FFFu + ((u >> 16) & 1u);   // RNE
  return (unsigned short)(u >> 16);
}

// async global->LDS, 16B per lane. LDS dest is wave-uniform base; HW does base + lane*16.
__device__ __forceinline__ void async16(const void* g, void* l) {
  __builtin_amdgcn_global_load_lds((__attribute__((address_space(1))) void*)(g),
                                   (__attribute__((address_space(3))) void*)(l),
                                   16, 0, 0);
}

// ---------------------------------------------------------------------------
// K_PREP v3: tri-role, BRANCHLESS buildx gathers (unchanged, FROZEN).
//   [0, 768):      buildx: (image, 22-col k-slice). 768 blocks = 3/CU.
//   [768, 1824):   gc_w -> gcwT bf16 transpose, 64x64 tiles.
//   [1824, 1888):  A2p[b][c pad128][n pad128] bf16 = X + adj (zero-padded)
// ---------------------------------------------------------------------------
__global__ __launch_bounds__(256) void k_prep(const float* __restrict__ gcw,
                                              unsigned short* __restrict__ gcwT,
                                              const float* __restrict__ imgf,
                                              const float* __restrict__ bbox,
                                              const float* __restrict__ lw,
                                              const float* __restrict__ lb,
                                              const int* __restrict__ labels,
                                              unsigned short* __restrict__ xbf,
                                              const float* __restrict__ X,
                                              const float* __restrict__ adj,
                                              unsigned short* __restrict__ A2p) {
  __shared__ float smf[64 * 65];   // 16.6 KB; buildx aliases lab/sidx/swt onto it
  const int bx  = blockIdx.x;
  const int tid = threadIdx.x;

  if (bx < 768) {
    // ---- buildx role ----
    int*   lab  = (int*)smf;           // [150]
    int*   sidx = lab + NBPER;         // [100][3]
    float* swt  = (float*)(sidx + 3 * CC);  // [100][3]
    const int bimg = bx / 12;
    const int sl   = bx - bimg * 12;   // cols [sl*22, sl*22+22)
    if (tid < NBPER) lab[tid] = labels[bimg * NBPER + tid];
    __syncthreads();
    if (tid < CC) {                    // parallel stable scan, branchless output
      int i0 = 0, i1 = 0, i2 = 0, cnt = 0;
      float w0 = 0.f, w1 = 0.f, w2 = 0.f;
      for (int i = 0; i < NBPER; ++i) {
        if (lab[i] == tid + 1) {
          if (cnt == 0)      { i0 = bimg * NBPER + i; w0 = lw[0]; }
          else if (cnt == 1) { i1 = bimg * NBPER + i; w1 = lw[1]; }
          else if (cnt == 2) { i2 = bimg * NBPER + i; w2 = lw[2]; }
          ++cnt;
        }
      }
      sidx[tid * 3] = i0; sidx[tid * 3 + 1] = i1; sidx[tid * 3 + 2] = i2;
      swt[tid * 3] = w0;  swt[tid * 3 + 1] = w1;  swt[tid * 3 + 2] = w2;
    }
    __syncthreads();
    const float bias = lb[0];
    for (int idx = tid; idx < CC * 22; idx += 256) {
      const int cl  = idx / 22;
      const int col = sl * 22 + (idx - cl * 22);   // 0..263
      const int d0  = col * 8;
      const int r   = bimg * CC + cl;
      const int i0 = sidx[cl * 3], i1 = sidx[cl * 3 + 1], i2 = sidx[cl * 3 + 2];
      const float w0 = swt[cl * 3], w1 = swt[cl * 3 + 1], w2 = swt[cl * 3 + 2];
      float v[8];
      if (d0 < 2048) {
        // 6 unconditional, independent loads (full MLP), then FMA
        const float4* p0 = (const float4*)(imgf + (size_t)i0 * 2048 + d0);
        const float4* p1 = (const float4*)(imgf + (size_t)i1 * 2048 + d0);
        const float4* p2 = (const float4*)(imgf + (size_t)i2 * 2048 + d0);
        float4 a0 = p0[0], a1 = p0[1];
        float4 b0 = p1[0], b1 = p1[1];
        float4 c0 = p2[0], c1 = p2[1];
        v[0] = bias + w0 * a0.x + w1 * b0.x + w2 * c0.x;
        v[1] = bias + w0 * a0.y + w1 * b0.y + w2 * c0.y;
        v[2] = bias + w0 * a0.z + w1 * b0.z + w2 * c0.z;
        v[3] = bias + w0 * a0.w + w1 * b0.w + w2 * c0.w;
        v[4] = bias + w0 * a1.x + w1 * b1.x + w2 * c1.x;
        v[5] = bias + w0 * a1.y + w1 * b1.y + w2 * c1.y;
        v[6] = bias + w0 * a1.z + w1 * b1.z + w2 * c1.z;
        v[7] = bias + w0 * a1.w + w1 * b1.w + w2 * c1.w;
      } else if (d0 == 2048) {
        float4 u0 = *(const float4*)(bbox + (size_t)i0 * 4);
        float4 u1 = *(const float4*)(bbox + (size_t)i1 * 4);
        float4 u2 = *(const float4*)(bbox + (size_t)i2 * 4);
        v[0] = bias + w0 * u0.x + w1 * u1.x + w2 * u2.x;
        v[1] = bias + w0 * u0.y + w1 * u1.y + w2 * u2.y;
        v[2] = bias + w0 * u0.z + w1 * u1.z + w2 * u2.z;
        v[3] = bias + w0 * u0.w + w1 * u1.w + w2 * u2.w;
        v[4] = 0.f; v[5] = 0.f; v[6] = 0.f; v[7] = 0.f;
      } else {
#pragma unroll
        for (int q = 0; q < 8; ++q) v[q] = 0.f;
      }
      unsigned short o[8] __attribute__((aligned(16)));
#pragma unroll
      for (int q = 0; q < 8; ++q) o[q] = f2bf(v[q]);
      *(uint4*)(xbf + (size_t)r * KP + d0) = *(const uint4*)o;
    }
    return;
  }

  if (bx < 1824) {
    // ---- transpose role: 64x64 tile ----
    const int t  = bx - 768;       // 0..1055
    const int ko = t % 33;
    const int oo = t / 33;
    const int cc = tid & 63, r0 = tid >> 6;
#pragma unroll
    for (int i = 0; i < 16; ++i) {
      const int r = r0 * 16 + i;
      const int k = ko * 64 + r;
      smf[r * 65 + cc] = (k < FEAT) ? gcw[(size_t)k * NOUT + oo * 64 + cc] : 0.f;
    }
    __syncthreads();
    const int ol = tid >> 2;       // 0..63
    const int kq = tid & 3;        // covers 16 k's
    unsigned short buf[16] __attribute__((aligned(16)));
#pragma unroll
    for (int j = 0; j < 16; ++j) buf[j] = f2bf(smf[(kq * 16 + j) * 65 + ol]);
    const size_t base = (size_t)(oo * 64 + ol) * KP + ko * 64 + kq * 16;
    *(uint4*)&gcwT[base]     = *(const uint4*)&buf[0];
    *(uint4*)&gcwT[base + 8] = *(const uint4*)&buf[8];
    return;
  }

  // ---- A2p role ----
  {
    const int b = bx - 1824;
#pragma unroll
    for (int it = 0; it < 16; ++it) {
      const int idx = it * 256 + tid;
      const int c = idx >> 5, ng = idx & 31;
      const int n = ng * 4;
      unsigned short pk[4] __attribute__((aligned(8))) = {0, 0, 0, 0};
      if (c < CC && n < CC) {   // n multiple of 4 -> n+3 <= 99
        const float4 a4 = *(const float4*)(adj + (size_t)b * (CC * CC) + c * CC + n);
        const float4 x4 = *(const float4*)(X + c * CC + n);
        pk[0] = f2bf(a4.x + x4.x); pk[1] = f2bf(a4.y + x4.y);
        pk[2] = f2bf(a4.z + x4.z); pk[3] = f2bf(a4.w + x4.w);
      }
      *(uint2*)&A2p[((size_t)b * 128 + c) * 128 + n] = *(const uint2*)pk;
    }
  }
}

// ---------------------------------------------------------------------------
// KC v2: support = x_bf16 @ gcwT^T -> supportT[b][o][n pad 128] bf16.
// 256x256 tile, BK=64, 512 thr (8 waves = 2M x 4N, each wave 128x64 out),
// 8-phase pipelined schedule (T3+T4): per phase {ds_read subtile || stage one
// 128x64 half-tile via global_load_lds | BAR | setprio(1) 16xMFMA setprio(0)
// | BAR}; counted s_waitcnt vmcnt(6) ONLY at phases 4 and 8 -- 3 half-tiles
// (6 load instrs/wave) always in flight, never drained in the main loop.
// Per-tile stage order [B0,B1,A0,A1] + quadrant order (M0N0)(M0N1)(M1N0)(M1N1)
// guarantees each half-tile's last reader barriers out before its slot is
// re-staged. K = 33 tiles: 15 full iters + peeled iter (stage stops) + 1-tile
// tail, drain vmcnt 6 -> 0. Same 8-row k-rotation swizzle as before on both
// the pre-swizzled global source and the ds_read side (conflict-free b128).
// LDS 128 KiB -> 1 block/CU; XCD swizzle gives each XCD one 256-col B panel
// (1.08 MB, L2-resident).
// ---------------------------------------------------------------------------
__global__ __launch_bounds__(512, 2) void k_gemm1(const unsigned short* __restrict__ Ax,
                                                  const unsigned short* __restrict__ Bx,
                                                  unsigned short* __restrict__ ST) {
  __shared__ unsigned short sh[2][2][16384] __attribute__((aligned(16)));  // [dbuf][A|B][256*64]
  const int tid  = threadIdx.x;
  const int lane = tid & 63;
  const int w    = tid >> 6;          // 0..7
  const int wr   = w >> 2;            // 0..1  (M half of the tile)
  const int wc   = w & 3;             // 0..3  (N quarter)
  const int srow = lane >> 3;                      // row within 8-row chunk
  const int gk   = (((lane & 7) - srow) & 7) * 8;  // swizzle-inverse k start
  const int quad = lane >> 4;
  const int lrow = lane & 15;
  const int rot  = (lane & 7) * 8;
  // XCD-aware swizzle: 200 wgs, 8 XCDs, 25 per XCD; each XCD owns one ncol.
  const int v    = (blockIdx.x & 7) * 25 + (blockIdx.x >> 3);
  const int ncol = v / 25;            // 0..7
  const int mrow = v - ncol * 25;     // 0..24
  const int m0   = mrow * 256;
  const int n0   = ncol * 256;
  const int wm   = wr * 128;
  const int wn   = wc * 64;

  const unsigned short* pA = Ax + (size_t)(m0 + w * 8 + srow) * KP + gk;
  const unsigned short* pB = Bx + (size_t)(n0 + w * 8 + srow) * KP + gk;

  floatx4 acc[8][4] = {};
  short8  afrag[4][2], bfrag[4][2];

#define STG_A(DB, HH, K0) do {                                            \
    const unsigned short* s_ = pA + (size_t)((HH) * 128) * KP + (K0);     \
    async16(s_,           &sh[DB][0][(HH) * 8192 + w * 512]);             \
    async16(s_ + 64 * KP, &sh[DB][0][(HH) * 8192 + (8 + w) * 512]);       \
  } while (0)
#define STG_B(DB, HH, K0) do {                                            \
    const unsigned short* s_ = pB + (size_t)((HH) * 128) * KP + (K0);     \
    async16(s_,           &sh[DB][1][(HH) * 8192 + w * 512]);             \
    async16(s_ + 64 * KP, &sh[DB][1][(HH) * 8192 + (8 + w) * 512]);       \
  } while (0)
#define RD_B(DB) do {                                                     \
    _Pragma("unroll") for (int g = 0; g < 4; ++g)                         \
    _Pragma("unroll") for (int kk = 0; kk < 2; ++kk)                      \
      bfrag[g][kk] = *(const short8*)&sh[DB][1][(wn + g * 16 + lrow) * 64 \
                                    + ((kk * 32 + quad * 8 + rot) & 63)]; \
  } while (0)
#define RD_A(DB, FO) do {                                                 \
    _Pragma("unroll") for (int f = 0; f < 4; ++f)                         \
    _Pragma("unroll") for (int kk = 0; kk < 2; ++kk)                      \
      afrag[f][kk] = *(const short8*)&sh[DB][0][(wm + ((FO) + f) * 16 + lrow) * 64 \
                                    + ((kk * 32 + quad * 8 + rot) & 63)]; \
  } while (0)
#define MFMA_Q(FO, GO) do {                                               \
    __builtin_amdgcn_s_setprio(1);                                        \
    _Pragma("unroll") for (int f = 0; f < 4; ++f)                         \
    _Pragma("unroll") for (int g = 0; g < 2; ++g)                         \
    _Pragma("unroll") for (int kk = 0; kk < 2; ++kk)                      \
      acc[(FO) + f][(GO) + g] = __builtin_amdgcn_mfma_f32_16x16x32_bf16(  \
          afrag[f][kk], bfrag[(GO) + g][kk], acc[(FO) + f][(GO) + g], 0, 0, 0); \
    __builtin_amdgcn_s_setprio(0);                                        \
  } while (0)
#define BAR __builtin_amdgcn_s_barrier()
#define VM6 asm volatile("s_waitcnt vmcnt(6)" ::: "memory")
#define VM0 asm volatile("s_waitcnt vmcnt(0)" ::: "memory")

  // prologue: H0..H6 = t0{B0,B1,A0,A1}, t1{B0,B1,A0}; wait tile0 (6 instrs in flight)
  STG_B(0, 0, 0);  STG_B(0, 1, 0);  STG_A(0, 0, 0);  STG_A(0, 1, 0);
  STG_B(1, 0, 64); STG_B(1, 1, 64); STG_A(1, 0, 64);
  VM6; BAR;

#pragma unroll 1
  for (int i = 0; i < 15; ++i) {      // tiles T=2i, T+1; stage T+1.A1 .. T+3.A0
    const int kT1 = i * 128 + 64, kT2 = i * 128 + 128, kT3 = i * 128 + 192;
    RD_B(0); RD_A(0, 0); STG_A(1, 1, kT1); BAR; MFMA_Q(0, 0); BAR;       // ph1
    STG_B(0, 0, kT2);                      BAR; MFMA_Q(0, 2); BAR;       // ph2
    RD_A(0, 4); STG_B(0, 1, kT2);          BAR; MFMA_Q(4, 0); BAR;       // ph3
    STG_A(0, 0, kT2);                      BAR; MFMA_Q(4, 2); VM6; BAR;  // ph4
    RD_B(1); RD_A(1, 0); STG_A(0, 1, kT2); BAR; MFMA_Q(0, 0); BAR;       // ph5
    STG_B(1, 0, kT3);                      BAR; MFMA_Q(0, 2); BAR;       // ph6
    RD_A(1, 4); STG_B(1, 1, kT3);          BAR; MFMA_Q(4, 0); BAR;       // ph7
    STG_A(1, 0, kT3);                      BAR; MFMA_Q(4, 2); VM6; BAR;  // ph8
  }
  // peeled iter 15 (tiles 30,31): stage 31.A1 + all of tile 32, then drain
  RD_B(0); RD_A(0, 0); STG_A(1, 1, 1984); BAR; MFMA_Q(0, 0); BAR;
  STG_B(0, 0, 2048);                      BAR; MFMA_Q(0, 2); BAR;
  RD_A(0, 4); STG_B(0, 1, 2048);          BAR; MFMA_Q(4, 0); BAR;
  STG_A(0, 0, 2048);                      BAR; MFMA_Q(4, 2); VM6; BAR;
  RD_B(1); RD_A(1, 0); STG_A(0, 1, 2048); BAR; MFMA_Q(0, 0); BAR;
                                          BAR; MFMA_Q(0, 2); BAR;
  RD_A(1, 4);                             BAR; MFMA_Q(4, 0); BAR;
                                          BAR; MFMA_Q(4, 2); VM0; BAR;
  // tail: tile 32 (even -> buf0), everything resident, no staging
  RD_B(0); RD_A(0, 0); MFMA_Q(0, 0); MFMA_Q(0, 2);
  RD_A(0, 4);          MFMA_Q(4, 0); MFMA_Q(4, 2);

#undef STG_A
#undef STG_B
#undef RD_A
#undef RD_B
#undef MFMA_Q
#undef BAR
#undef VM6
#undef VM0

  // epilogue: acc(row=m_local, col=o_local) -> LDS T[o][m] (stride 264) in two
  // 128-o halves, then coalesced uint stores into ST[b][n0+o][c]
  // ((c,c+1) never straddle b: m even).
  __syncthreads();
  {
    unsigned short* Tb = &sh[0][0][0];
#pragma unroll
    for (int h = 0; h < 2; ++h) {
      if (h) __syncthreads();
      if ((wc >> 1) == h) {          // waves whose 64 cols lie in this o-half
#pragma unroll
        for (int f = 0; f < 8; ++f) {
#pragma unroll
          for (int g = 0; g < 4; ++g) {
            const int ol = (wc & 1) * 64 + g * 16 + lrow;     // 0..127
#pragma unroll
            for (int rr = 0; rr < 4; ++rr) {
              const int ml = wm + f * 16 + quad * 4 + rr;     // 0..255
              Tb[ol * 264 + ml] = f2bf(acc[f][g][rr]);
            }
          }
        }
      }
      __syncthreads();
#pragma unroll
      for (int it = 0; it < 32; ++it) {
        const int idx = it * 512 + tid;
        const int o = idx >> 7;            // 0..127
        const int m = (idx & 127) * 2;     // even
        const int r = m0 + m;
        const int b = (r * 5243) >> 19;    // r/100
        const int c = r - b * 100;         // even; (c,c+1) same b
        const unsigned int val = *(const unsigned int*)&Tb[o * 264 + m];
        *(unsigned int*)&ST[((size_t)b * NOUT + n0 + h * 128 + o) * 128 + c] = val;
      }
    }
  }
}

// ---------------------------------------------------------------------------
// KD: out[b,o] = sum_c g[b,c]*lrelu( sum_n A2[c,n] * S[b,n,o] + gc_b[o] )
// bf16 MFMA; BOTH operands async16-staged from pre-packed A2p / supportT.
// ST pad n>=100 may be garbage; A2p cols are zero there so products vanish.
// FROZEN since R7.
// ---------------------------------------------------------------------------
__global__ __launch_bounds__(256) void k_gemm2(const unsigned short* __restrict__ A2p,
                                               const unsigned short* __restrict__ ST,
                                               const float* __restrict__ gf,
                                               const float* __restrict__ gcb,
                                               float* __restrict__ outp) {
  __shared__ unsigned short A2s[128 * 64] __attribute__((aligned(16)));
  __shared__ unsigned short Ssm[128 * 64] __attribute__((aligned(16)));
  __shared__ float gsm[128];
  __shared__ float red[128 * 9];
  const int tid = threadIdx.x;
  const int o0  = blockIdx.x * 128;
  const int b   = blockIdx.y;
  if (tid < 128) gsm[tid] = (tid < CC) ? gf[b * CC + tid] : 0.f;

  const int lane = tid & 63;
  const int w    = tid >> 6;
  const int srow = lane >> 3;
  const int gk   = (((lane & 7) - srow) & 7) * 8;
  const int quad = lane >> 4;
  const int lrow = lane & 15;
  const int rot  = (lane & 7) * 8;
  const int wm   = (w & 1) * 64;
  const int wn   = (w >> 1) * 64;

  floatx4 acc[4][4] = {};

  for (int kb = 0; kb < 2; ++kb) {
    const int k0 = kb * 64;
    __syncthreads();  // protect LDS reuse across kb (and gsm ordering)
#pragma unroll
    for (int t = 0; t < 4; ++t) {
      const int chunk = t * 4 + w;
      const int row = chunk * 8 + srow;
      async16(A2p + ((size_t)b * 128 + row) * 128 + k0 + gk, &A2s[chunk * 512]);
      async16(ST + ((size_t)b * NOUT + o0 + row) * 128 + k0 + gk, &Ssm[chunk * 512]);
    }
    __syncthreads();
#pragma unroll
    for (int kp = 0; kp < 2; ++kp) {
      const int koff = (kp * 32 + quad * 8 + rot) & 63;
      short8 af[4], bfr[4];
#pragma unroll
      for (int i = 0; i < 4; ++i)
        af[i]  = *(const short8*)&A2s[(wm + i * 16 + lrow) * 64 + koff];
#pragma unroll
      for (int j = 0; j < 4; ++j)
        bfr[j] = *(const short8*)&Ssm[(wn + j * 16 + lrow) * 64 + koff];
#pragma unroll
      for (int i = 0; i < 4; ++i)
#pragma unroll
        for (int j = 0; j < 4; ++j)
          acc[i][j] = __builtin_amdgcn_mfma_f32_16x16x32_bf16(af[i], bfr[j], acc[i][j], 0, 0, 0);
    }
  }
  __syncthreads();

  // epilogue: out_o = sum_c g[c]*lrelu(T[c][o]+bias[o])
  const int slot = (w & 1) * 4 + quad;
#pragma unroll
  for (int j = 0; j < 4; ++j) {
    const int ol = wn + j * 16 + lrow;
    const float bias = gcb[o0 + ol];
    float s = 0.f;
#pragma unroll
    for (int i = 0; i < 4; ++i) {
#pragma unroll
      for (int rr = 0; rr < 4; ++rr) {
        const int c = wm + i * 16 + quad * 4 + rr;
        float t = acc[i][j][rr] + bias;
        t = (t > 0.f) ? t : 0.01f * t;
        s += gsm[c] * t;   // gsm[c]=0 masks c>=100 pad rows
      }
    }
    red[ol * 9 + slot] = s;
  }
  __syncthreads();
  if (tid < 128) {
    float s = 0.f;
#pragma unroll
    for (int t = 0; t < 8; ++t) s += red[tid * 9 + t];
    outp[(size_t)b * NOUT + o0 + tid] = s;
  }
}

// ---------------------------------------------------------------------------
extern "C" void kernel_launch(void* const* d_in, const int* in_sizes, int n_in,
                              void* d_out, int out_size, void* d_ws, size_t ws_size,
                              hipStream_t stream) {
  const float* imgf   = (const float*)d_in[0];
  const float* bbox   = (const float*)d_in[1];
  const float* gfeat  = (const float*)d_in[2];
  const float* adj    = (const float*)d_in[3];
  const float* X      = (const float*)d_in[4];
  const float* lw     = (const float*)d_in[5];
  const float* lb     = (const float*)d_in[6];
  const float* gcw    = (const float*)d_in[7];
  const float* gcb    = (const float*)d_in[8];
  const int*   labels = (const int*)d_in[9];

  char* ws = (char*)d_ws;
  // ws layout (~71.3 MB; ST must NOT overlay xbf -- gemm1 reads xbf while
  // writing ST):
  //   [0, 27,033,600)             xbf
  //   [27,033,600, 35,684,352)    gcwT
  //   [35,684,352, 69,238,784)    supportT [64][2048][128] bf16
  //   [69,238,784, 71,335,936)    A2p      [64][128][128] bf16
  unsigned short* xbf      = (unsigned short*)(ws);
  unsigned short* gcwT     = (unsigned short*)(ws + 27033600);
  unsigned short* supportT = (unsigned short*)(ws + 35684352);
  unsigned short* A2p      = (unsigned short*)(ws + 69238784);
  float*          outp     = (float*)d_out;

  k_prep<<<dim3(1888), dim3(256), 0, stream>>>(gcw, gcwT, imgf, bbox, lw, lb,
                                               labels, xbf, X, adj, A2p);
  k_gemm1<<<dim3(200), dim3(512), 0, stream>>>(xbf, gcwT, supportT);
  k_gemm2<<<dim3(NOUT / 128, BB), dim3(256), 0, stream>>>(A2p, supportT, gfeat, gcb, outp);
}